// Round 4
// baseline (7444.315 us; speedup 1.0000x reference)
//
#include <hip/hip_runtime.h>

// Seq2SeqLSTMForecaster on MI355X — round 4.
//  - kA  : enc L0 recurrence (split-k VALU, as round 2). Emits ys0 as THREE
//          bf16 planes (hi/mid/lo of a split-3 decomposition), coalesced.
//  - kX  : X1 = ys0 @ Wih1^T + b1 as bf16 split-3 MFMA (6 terms ~ fp32
//          accuracy). No LDS: A/B fragments are k-contiguous per lane and
//          load straight from the bf16 planes. D layout per m89:
//          col=lane&15, row=(lane>>4)*4+reg.
//  - kB2 : enc L1 recurrence (unchanged, reads fp32 X1).
//  - kD  : decoder (unchanged from round 3).

#define B_    1024
#define T_    672
#define H_    128
#define G_    512      // 4*H
#define TGT_  96
#define NBLK_ 256

typedef __attribute__((ext_vector_type(8))) short v8s;
typedef __attribute__((ext_vector_type(4))) float v4f;

__device__ __forceinline__ float sigm(float x)   { return 1.f / (1.f + __expf(-x)); }
__device__ __forceinline__ float tanh_f(float x) { return 1.f - 2.f / (1.f + __expf(2.f * x)); }

__device__ __forceinline__ unsigned short f2bf(float x) {
    union { float f; unsigned u; } v; v.f = x;
    const unsigned r = (v.u + 0x7FFFu + ((v.u >> 16) & 1u)) >> 16;
    return (unsigned short)r;
}
__device__ __forceinline__ float bf2f(unsigned short b) {
    union { unsigned u; float f; } v; v.u = ((unsigned)b) << 16;
    return v.f;
}

// ---------------------------------------------------------------- prep ------
struct PrepArgs {
    const float* t_src[3];   // eWhh0, eWhh1, dWhh0 -> [128,512] transposes
    float*       t_dst[3];
    const float* wo1;  float* wo1T;
    const float* d1x;  const float* d1h;  float* pack;   // dec L1 interleave
    const float* wih1; unsigned short *Bh, *Bm, *Bl;     // enc Wih1 split-3 planes [512][128]
};

__global__ void kPrep(PrepArgs a) {
    const int m = blockIdx.x;
    if (m < 3) {
        for (int i = threadIdx.x; i < G_ * H_; i += blockDim.x) {
            const int j = i >> 7, k = i & 127;
            a.t_dst[m][k * G_ + j] = a.t_src[m][i];
        }
    } else if (m == 3) {
        for (int i = threadIdx.x; i < H_ * H_; i += blockDim.x) {
            const int j = i >> 7, k = i & 127;
            a.wo1T[k * H_ + j] = a.wo1[i];
        }
    } else if (m == 4) {
        // pack[(k*512 + j)*2 + {0,1}] = {dWih1[j][k], dWhh1[j][k]}
        for (int i = threadIdx.x; i < G_ * H_; i += blockDim.x) {
            const int j = i & 511, k = i >> 9;
            a.pack[(k * G_ + j) * 2 + 0] = a.d1x[j * H_ + k];
            a.pack[(k * G_ + j) * 2 + 1] = a.d1h[j * H_ + k];
        }
    } else {
        // split-3 planes of enc Wih1, same [n][k] row-major layout
        for (int i = threadIdx.x; i < G_ * H_; i += blockDim.x) {
            const float v = a.wih1[i];
            const unsigned short hi = f2bf(v);
            const float r1 = v - bf2f(hi);
            const unsigned short mi = f2bf(r1);
            const float r2 = r1 - bf2f(mi);
            a.Bh[i] = hi; a.Bm[i] = mi; a.Bl[i] = f2bf(r2);
        }
    }
}

// ------------------------------------------------------- enc L0 (split-k) ---
__global__ __launch_bounds__(1024, 4) void kA(
    const float* __restrict__ feat,   // [B,T]
    const float* __restrict__ whhT,   // [128,512] enc_Whh0^T
    const float* __restrict__ wih0,   // [512]
    const float* __restrict__ bias,   // [512]
    unsigned short* __restrict__ ysh, // [CL][B][H] split-3 planes of h0
    unsigned short* __restrict__ ysm,
    unsigned short* __restrict__ ysl,
    float* __restrict__ hS, float* __restrict__ cS,
    int t0, int CL)
{
    __shared__ __align__(16) float h_sh[H_ * 4];     // [hid][bb]
    __shared__ __align__(16) float zp[2 * 4 * G_];
    __shared__ __align__(16) float f_sh[84 * 4];

    const int tid = threadIdx.x;
    const int j   = tid & (G_ - 1);
    const int kh  = tid >> 9;
    const int B0  = blockIdx.x * 4;

    float w[64];
#pragma unroll
    for (int k = 0; k < 64; k++) w[k] = whhT[(kh * 64 + k) * G_ + j];
    const float wx = wih0[j];
    const float bj = bias[j];

    for (int i = tid; i < CL * 4; i += 1024)
        f_sh[i] = feat[(B0 + (i & 3)) * T_ + t0 + (i >> 2)];

    float c = 0.f;
    if (tid < 512) {
        const int hid = tid & 127, bb = tid >> 7;
        float hv = 0.f;
        if (t0 != 0) { c = cS[(B0 + bb) * H_ + hid]; hv = hS[(B0 + bb) * H_ + hid]; }
        h_sh[hid * 4 + bb] = hv;
    }
    __syncthreads();

    const float* hb = h_sh + kh * 64 * 4;
    for (int dt = 0; dt < CL; dt++) {
        float a0, a1, a2, a3;
        if (kh == 0) {
            const float4 xv = *(const float4*)&f_sh[dt * 4];
            a0 = __fmaf_rn(xv.x, wx, bj);
            a1 = __fmaf_rn(xv.y, wx, bj);
            a2 = __fmaf_rn(xv.z, wx, bj);
            a3 = __fmaf_rn(xv.w, wx, bj);
        } else { a0 = a1 = a2 = a3 = 0.f; }
#pragma unroll
        for (int k = 0; k < 64; k++) {
            const float4 h4 = *(const float4*)&hb[k * 4];   // wave-uniform broadcast
            a0 = __fmaf_rn(h4.x, w[k], a0);
            a1 = __fmaf_rn(h4.y, w[k], a1);
            a2 = __fmaf_rn(h4.z, w[k], a2);
            a3 = __fmaf_rn(h4.w, w[k], a3);
        }
        zp[kh * 2048 + 0 * G_ + j] = a0;
        zp[kh * 2048 + 1 * G_ + j] = a1;
        zp[kh * 2048 + 2 * G_ + j] = a2;
        zp[kh * 2048 + 3 * G_ + j] = a3;
        __syncthreads();

        if (tid < 512) {
            const int hid = tid & 127, bb = tid >> 7;
            const int base = bb * G_ + hid;
            const float zi = zp[base]           + zp[2048 + base];
            const float zf = zp[base + H_]      + zp[2048 + base + H_];
            const float zg = zp[base + 2 * H_]  + zp[2048 + base + 2 * H_];
            const float zo = zp[base + 3 * H_]  + zp[2048 + base + 3 * H_];
            c = sigm(zf) * c + sigm(zi) * tanh_f(zg);
            const float h = sigm(zo) * tanh_f(c);
            h_sh[hid * 4 + bb] = h;
            // split-3 emit (coalesced: lanes = consecutive hid)
            const unsigned short hh = f2bf(h);
            const float r1 = h - bf2f(hh);
            const unsigned short hm = f2bf(r1);
            const float r2 = r1 - bf2f(hm);
            const size_t o = (size_t)dt * (B_ * H_) + (B0 + bb) * H_ + hid;
            ysh[o] = hh; ysm[o] = hm; ysl[o] = f2bf(r2);
        }
        __syncthreads();
    }
    if (tid < 512) {
        const int hid = tid & 127, bb = tid >> 7;
        hS[(B0 + bb) * H_ + hid] = h_sh[hid * 4 + bb];
        cS[(B0 + bb) * H_ + hid] = c;
    }
}

// ------------------------------------------------- X1 GEMM via MFMA split-3 -
// X1[dt][b][n] = sum_k ys0[dt][b][k] * Wih1[n][k] + bias[n]
// A = ys0 planes [dt][b=M][k], B = Wih1 planes [n=N][k]. Both frag-native:
// per-lane 8 contiguous k. 6 split terms ~ fp32 accuracy.
__global__ __launch_bounds__(256, 4) void kX(
    const unsigned short* __restrict__ Ah, const unsigned short* __restrict__ Am,
    const unsigned short* __restrict__ Al,
    const unsigned short* __restrict__ Bh, const unsigned short* __restrict__ Bm,
    const unsigned short* __restrict__ Bl,
    const float* __restrict__ bias,
    float* __restrict__ X1)           // [CL][1024][512]
{
    const int tid  = threadIdx.x;
    const int w    = tid >> 6;
    const int lane = tid & 63;
    const int mr   = lane & 15;       // A-row (batch) / B-row (gate) / D-col
    const int q    = lane >> 4;       // k-quad
    const int m0   = blockIdx.x * 64 + w * 16;
    const int n0   = blockIdx.y * 64;
    const int dt   = blockIdx.z;

    const size_t aoff = ((size_t)dt * B_ + m0 + mr) * H_ + q * 8;
    const unsigned short* pah = Ah + aoff;
    const unsigned short* pam = Am + aoff;
    const unsigned short* pal = Al + aoff;

    v4f acc[4];
#pragma unroll
    for (int nt = 0; nt < 4; nt++) acc[nt] = (v4f)0.f;

#pragma unroll
    for (int kt = 0; kt < 4; kt++) {
        const v8s a_h = *(const v8s*)(pah + kt * 32);
        const v8s a_m = *(const v8s*)(pam + kt * 32);
        const v8s a_l = *(const v8s*)(pal + kt * 32);
#pragma unroll
        for (int nt = 0; nt < 4; nt++) {
            const size_t boff = (size_t)(n0 + nt * 16 + mr) * H_ + kt * 32 + q * 8;
            const v8s b_h = *(const v8s*)(Bh + boff);
            const v8s b_m = *(const v8s*)(Bm + boff);
            const v8s b_l = *(const v8s*)(Bl + boff);
            v4f t = acc[nt];
            t = __builtin_amdgcn_mfma_f32_16x16x32_bf16(a_m, b_m, t, 0, 0, 0);
            t = __builtin_amdgcn_mfma_f32_16x16x32_bf16(a_h, b_l, t, 0, 0, 0);
            t = __builtin_amdgcn_mfma_f32_16x16x32_bf16(a_l, b_h, t, 0, 0, 0);
            t = __builtin_amdgcn_mfma_f32_16x16x32_bf16(a_h, b_m, t, 0, 0, 0);
            t = __builtin_amdgcn_mfma_f32_16x16x32_bf16(a_m, b_h, t, 0, 0, 0);
            t = __builtin_amdgcn_mfma_f32_16x16x32_bf16(a_h, b_h, t, 0, 0, 0);
            acc[nt] = t;
        }
    }

    // D: col = lane&15 (n), row = q*4 + reg (m)  [m89]
#pragma unroll
    for (int nt = 0; nt < 4; nt++) {
        const int ng = n0 + nt * 16 + mr;
        const float bv = bias[ng];
#pragma unroll
        for (int r = 0; r < 4; r++) {
            X1[((size_t)dt * B_ + m0 + q * 4 + r) * G_ + ng] = acc[nt][r] + bv;
        }
    }
}

// ----------------------------------------- enc L1 recurrent-only (split-k) --
__global__ __launch_bounds__(1024, 4) void kB2(
    const float* __restrict__ X1,     // [CL][B][512] x-projection (+bias)
    const float* __restrict__ whhT,   // [128,512] enc_Whh1^T
    float* __restrict__ hS, float* __restrict__ cS,
    int t0, int CL)
{
    __shared__ __align__(16) float h_sh[H_ * 4];
    __shared__ __align__(16) float zp[2 * 4 * G_];

    const int tid = threadIdx.x;
    const int j   = tid & (G_ - 1);
    const int kh  = tid >> 9;
    const int B0  = blockIdx.x * 4;

    float w[64];
#pragma unroll
    for (int k = 0; k < 64; k++) w[k] = whhT[(kh * 64 + k) * G_ + j];

    float c = 0.f;
    if (tid < 512) {
        const int hid = tid & 127, bb = tid >> 7;
        float hv = 0.f;
        if (t0 != 0) { c = cS[(B0 + bb) * H_ + hid]; hv = hS[(B0 + bb) * H_ + hid]; }
        h_sh[hid * 4 + bb] = hv;
    }
    __syncthreads();

    const float* hb = h_sh + kh * 64 * 4;
    for (int dt = 0; dt < CL; dt++) {
        float xg0 = 0.f, xg1 = 0.f, xg2 = 0.f, xg3 = 0.f;
        if (kh == 0) {
            const size_t xb = ((size_t)dt * B_ + B0 + (j >> 7)) * G_ + (j & 127);
            xg0 = X1[xb];
            xg1 = X1[xb + H_];
            xg2 = X1[xb + 2 * H_];
            xg3 = X1[xb + 3 * H_];
        }
        float a0 = 0.f, a1 = 0.f, a2 = 0.f, a3 = 0.f;
#pragma unroll
        for (int k = 0; k < 64; k++) {
            const float4 h4 = *(const float4*)&hb[k * 4];
            a0 = __fmaf_rn(h4.x, w[k], a0);
            a1 = __fmaf_rn(h4.y, w[k], a1);
            a2 = __fmaf_rn(h4.z, w[k], a2);
            a3 = __fmaf_rn(h4.w, w[k], a3);
        }
        zp[kh * 2048 + 0 * G_ + j] = a0;
        zp[kh * 2048 + 1 * G_ + j] = a1;
        zp[kh * 2048 + 2 * G_ + j] = a2;
        zp[kh * 2048 + 3 * G_ + j] = a3;
        __syncthreads();

        if (tid < 512) {
            const int hid = tid & 127, bb = tid >> 7;
            const int base = bb * G_ + hid;
            const float zi = zp[base]           + zp[2048 + base]           + xg0;
            const float zf = zp[base + H_]      + zp[2048 + base + H_]      + xg1;
            const float zg = zp[base + 2 * H_]  + zp[2048 + base + 2 * H_]  + xg2;
            const float zo = zp[base + 3 * H_]  + zp[2048 + base + 3 * H_]  + xg3;
            c = sigm(zf) * c + sigm(zi) * tanh_f(zg);
            h_sh[hid * 4 + bb] = sigm(zo) * tanh_f(c);
        }
        __syncthreads();
    }
    if (tid < 512) {
        const int hid = tid & 127, bb = tid >> 7;
        hS[(B0 + bb) * H_ + hid] = h_sh[hid * 4 + bb];
        cS[(B0 + bb) * H_ + hid] = c;
    }
}

// --------------------------------------------------- decoder (split-k 1024) -
__global__ __launch_bounds__(1024, 4) void kD(
    const float* __restrict__ h1S, const float* __restrict__ c1S,
    const float* __restrict__ h2S, const float* __restrict__ c2S,
    const float* __restrict__ whh0T,  // [128][512] dec_Whh0^T (register-resident)
    const float* __restrict__ wih0,   // [512]
    const float* __restrict__ b0,
    const float* __restrict__ packD1, // [128][512][2] interleaved {Wih1,Whh1}^T
    const float* __restrict__ b1,
    const float* __restrict__ wo1T,   // [128][128] (staged to LDS)
    const float* __restrict__ bo1,
    const float* __restrict__ wo2,
    const float* __restrict__ bo2,
    float* __restrict__ out)          // [B,TGT]
{
    __shared__ __align__(16) float h1_sh[H_ * 4];
    __shared__ __align__(16) float h2_sh[H_ * 4];
    __shared__ __align__(16) float zp[2 * 4 * G_];
    __shared__ __align__(16) float wo1s[H_ * H_];
    __shared__ __align__(16) float x_sh[4];
    __shared__ float rp[8];

    const int tid = threadIdx.x;
    const int j   = tid & (G_ - 1);
    const int kh  = tid >> 9;
    const int B0  = blockIdx.x * 4;

    float w0[64];
#pragma unroll
    for (int k = 0; k < 64; k++) w0[k] = whh0T[(kh * 64 + k) * G_ + j];
    const float wx0 = wih0[j];
    const float b0j = b0[j];
    const float b1j = b1[j];

    for (int t = tid; t < H_ * H_ / 4; t += 1024)
        *(float4*)&wo1s[t * 4] = *(const float4*)&wo1T[t * 4];

    const int hid = tid & 127, bb = (tid >> 7) & 3;
    float c1 = 0.f, c2 = 0.f, wo2v = 0.f, bo1j = 0.f;
    if (tid < 512) {
        c1 = c1S[(B0 + bb) * H_ + hid];
        c2 = c2S[(B0 + bb) * H_ + hid];
        h1_sh[hid * 4 + bb] = h1S[(B0 + bb) * H_ + hid];
        h2_sh[hid * 4 + bb] = h2S[(B0 + bb) * H_ + hid];
        wo2v = wo2[hid];
        bo1j = bo1[hid];
    }
    const float bo2v = bo2[0];
    if (tid < 4) x_sh[tid] = 0.f;
    __syncthreads();

    const float* hb1 = h1_sh + kh * 64 * 4;
    const float* hb2 = h2_sh + kh * 64 * 4;
    const float* pk  = packD1 + (size_t)kh * 64 * 1024 + (size_t)j * 2;

    for (int s = 0; s < TGT_; s++) {
        float a0, a1, a2, a3;
        if (kh == 0) {
            const float4 xv = *(const float4*)x_sh;
            a0 = __fmaf_rn(xv.x, wx0, b0j);
            a1 = __fmaf_rn(xv.y, wx0, b0j);
            a2 = __fmaf_rn(xv.z, wx0, b0j);
            a3 = __fmaf_rn(xv.w, wx0, b0j);
        } else { a0 = a1 = a2 = a3 = 0.f; }
#pragma unroll
        for (int k = 0; k < 64; k++) {
            const float4 h4 = *(const float4*)&hb1[k * 4];
            a0 = __fmaf_rn(h4.x, w0[k], a0);
            a1 = __fmaf_rn(h4.y, w0[k], a1);
            a2 = __fmaf_rn(h4.z, w0[k], a2);
            a3 = __fmaf_rn(h4.w, w0[k], a3);
        }
        zp[kh * 2048 + 0 * G_ + j] = a0;
        zp[kh * 2048 + 1 * G_ + j] = a1;
        zp[kh * 2048 + 2 * G_ + j] = a2;
        zp[kh * 2048 + 3 * G_ + j] = a3;
        __syncthreads();

        if (tid < 512) {
            const int base = bb * G_ + hid;
            const float zi = zp[base]           + zp[2048 + base];
            const float zf = zp[base + H_]      + zp[2048 + base + H_];
            const float zg = zp[base + 2 * H_]  + zp[2048 + base + 2 * H_];
            const float zo = zp[base + 3 * H_]  + zp[2048 + base + 3 * H_];
            c1 = sigm(zf) * c1 + sigm(zi) * tanh_f(zg);
            h1_sh[hid * 4 + bb] = sigm(zo) * tanh_f(c1);
        }
        __syncthreads();

        float d0, d1, d2, d3;
        if (kh == 0) { d0 = d1 = d2 = d3 = b1j; } else { d0 = d1 = d2 = d3 = 0.f; }
#pragma unroll 8
        for (int k = 0; k < 64; k++) {
            const float2 wp = *(const float2*)&pk[(size_t)k * 1024];
            const float4 p4 = *(const float4*)&hb1[k * 4];
            const float4 q4 = *(const float4*)&hb2[k * 4];
            d0 = __fmaf_rn(p4.x, wp.x, __fmaf_rn(q4.x, wp.y, d0));
            d1 = __fmaf_rn(p4.y, wp.x, __fmaf_rn(q4.y, wp.y, d1));
            d2 = __fmaf_rn(p4.z, wp.x, __fmaf_rn(q4.z, wp.y, d2));
            d3 = __fmaf_rn(p4.w, wp.x, __fmaf_rn(q4.w, wp.y, d3));
        }
        zp[kh * 2048 + 0 * G_ + j] = d0;
        zp[kh * 2048 + 1 * G_ + j] = d1;
        zp[kh * 2048 + 2 * G_ + j] = d2;
        zp[kh * 2048 + 3 * G_ + j] = d3;
        __syncthreads();

        if (tid < 512) {
            const int base = bb * G_ + hid;
            const float zi = zp[base]           + zp[2048 + base];
            const float zf = zp[base + H_]      + zp[2048 + base + H_];
            const float zg = zp[base + 2 * H_]  + zp[2048 + base + 2 * H_];
            const float zo = zp[base + 3 * H_]  + zp[2048 + base + 3 * H_];
            c2 = sigm(zf) * c2 + sigm(zi) * tanh_f(zg);
            h2_sh[hid * 4 + bb] = sigm(zo) * tanh_f(c2);
        }
        __syncthreads();

        if (tid < 512) {
            float acc = bo1j;
#pragma unroll 8
            for (int k = 0; k < H_; k++)
                acc = __fmaf_rn(h2_sh[k * 4 + bb], wo1s[k * H_ + hid], acc);
            float p = fmaxf(acc, 0.f) * wo2v;
            p += __shfl_down(p, 32);
            p += __shfl_down(p, 16);
            p += __shfl_down(p, 8);
            p += __shfl_down(p, 4);
            p += __shfl_down(p, 2);
            p += __shfl_down(p, 1);
            if ((tid & 63) == 0) rp[tid >> 6] = p;
        }
        __syncthreads();
        if (tid < 4) {
            const float pr = rp[tid * 2] + rp[tid * 2 + 1] + bo2v;
            out[(B0 + tid) * TGT_ + s] = pr;
            x_sh[tid] = pr;
        }
        __syncthreads();
    }
}

// ---------------------------------------------------------------- launch ----
extern "C" void kernel_launch(void* const* d_in, const int* in_sizes, int n_in,
                              void* d_out, int out_size, void* d_ws, size_t ws_size,
                              hipStream_t stream) {
    const float* feat  = (const float*)d_in[0];
    const float* eWih0 = (const float*)d_in[1];
    const float* eWhh0 = (const float*)d_in[2];
    const float* eB0   = (const float*)d_in[3];
    const float* eWih1 = (const float*)d_in[4];
    const float* eWhh1 = (const float*)d_in[5];
    const float* eB1   = (const float*)d_in[6];
    const float* dWih0 = (const float*)d_in[7];
    const float* dWhh0 = (const float*)d_in[8];
    const float* dB0   = (const float*)d_in[9];
    const float* dWih1 = (const float*)d_in[10];
    const float* dWhh1 = (const float*)d_in[11];
    const float* dB1   = (const float*)d_in[12];
    const float* Wo1   = (const float*)d_in[13];
    const float* bo1   = (const float*)d_in[14];
    const float* Wo2   = (const float*)d_in[15];
    const float* bo2   = (const float*)d_in[16];

    const size_t SZ_BH = (size_t)B_ * H_;     // 131072
    const size_t SZ_W  = (size_t)G_ * H_;     // 65536

    // per-CL bytes: X1 (CL*1024*512*4) + 3 bf16 planes (CL*1024*128*2 each)
    const size_t perCL = (size_t)B_ * G_ * 4 + 3 * (size_t)B_ * H_ * 2;
    const size_t fixed_b = 8u * 1024 * 1024;  // conservative fixed carve
    static const int cands[] = {84, 56, 48, 42, 28, 24, 21, 16, 14, 12, 8, 7, 6, 4, 3, 2, 1};
    int CL = 1;
    for (int ci = 0; ci < 17; ci++) {
        if (fixed_b + (size_t)cands[ci] * perCL <= ws_size) { CL = cands[ci]; break; }
    }
    const int NC = T_ / CL;

    char* cur = (char*)d_ws;
    float* X1    = (float*)cur;  cur += (size_t)CL * B_ * G_ * 4;
    float* h1S   = (float*)cur;  cur += SZ_BH * 4;
    float* c1S   = (float*)cur;  cur += SZ_BH * 4;
    float* h2S   = (float*)cur;  cur += SZ_BH * 4;
    float* c2S   = (float*)cur;  cur += SZ_BH * 4;
    float* wtE0  = (float*)cur;  cur += SZ_W * 4;
    float* wtE1h = (float*)cur;  cur += SZ_W * 4;
    float* wtD0  = (float*)cur;  cur += SZ_W * 4;
    float* wtD1p = (float*)cur;  cur += 2 * SZ_W * 4;
    float* wtO1  = (float*)cur;  cur += (size_t)H_ * H_ * 4;
    unsigned short* ysh = (unsigned short*)cur;  cur += (size_t)CL * SZ_BH * 2;
    unsigned short* ysm = (unsigned short*)cur;  cur += (size_t)CL * SZ_BH * 2;
    unsigned short* ysl = (unsigned short*)cur;  cur += (size_t)CL * SZ_BH * 2;
    unsigned short* wBh = (unsigned short*)cur;  cur += SZ_W * 2;
    unsigned short* wBm = (unsigned short*)cur;  cur += SZ_W * 2;
    unsigned short* wBl = (unsigned short*)cur;  cur += SZ_W * 2;

    PrepArgs pa;
    pa.t_src[0] = eWhh0; pa.t_dst[0] = wtE0;
    pa.t_src[1] = eWhh1; pa.t_dst[1] = wtE1h;
    pa.t_src[2] = dWhh0; pa.t_dst[2] = wtD0;
    pa.wo1 = Wo1; pa.wo1T = wtO1;
    pa.d1x = dWih1; pa.d1h = dWhh1; pa.pack = wtD1p;
    pa.wih1 = eWih1; pa.Bh = wBh; pa.Bm = wBm; pa.Bl = wBl;
    kPrep<<<6, 256, 0, stream>>>(pa);

    for (int c = 0; c < NC; c++) {
        const int t0 = c * CL;
        kA<<<NBLK_, 1024, 0, stream>>>(feat, wtE0, eWih0, eB0, ysh, ysm, ysl, h1S, c1S, t0, CL);
        kX<<<dim3(16, 8, CL), 256, 0, stream>>>(ysh, ysm, ysl, wBh, wBm, wBl, eB1, X1);
        kB2<<<NBLK_, 1024, 0, stream>>>(X1, wtE1h, h2S, c2S, t0, CL);
    }
    kD<<<NBLK_, 1024, 0, stream>>>(h1S, c1S, h2S, c2S,
                                   wtD0, dWih0, dB0,
                                   wtD1p, dB1,
                                   wtO1, bo1, Wo2, bo2,
                                   (float*)d_out);
}

// Round 5
// 5535.621 us; speedup vs baseline: 1.3448x; 1.3448x over previous
//
#include <hip/hip_runtime.h>

// Seq2SeqLSTMForecaster on MI355X — round 5.
// Key change: DUAL-GATE threads in all recurrent kernels. The recurrent dot
// was LDS-broadcast-bound (1 uniform ds_read_b128 per k per wave; access
// count = waves * k/thread is invariant under split-k). Each thread now owns
// 2 gates (w[128] regs, 8 FMA per h4 read) at 512 thr/block -> LDS accesses
// per step halved. __launch_bounds__(512,2) -> VGPR cap 256, 8 waves/CU.
//  - kA  : enc L0 recurrence, dual-gate split-k; emits ys0T k-major for kX.
//  - kX  : fp32 tiled GEMM (round-3 version; MFMA experiment reverted).
//  - kB2 : enc L1 recurrence, dual-gate split-k, X1 prefetch before dot.
//  - kD  : decoder, dual-gate split-k 512thr; dec-L1 weights packed
//          [k][j2][4] -> ONE coalesced float4 per k per thread; head reads
//          h2 via uniform b128 from a transposed copy.

#define B_    1024
#define T_    672
#define H_    128
#define G_    512      // 4*H
#define TGT_  96
#define NBLK_ 256

__device__ __forceinline__ float sigm(float x)   { return 1.f / (1.f + __expf(-x)); }
__device__ __forceinline__ float tanh_f(float x) { return 1.f - 2.f / (1.f + __expf(2.f * x)); }

// ---------------------------------------------------------------- prep ------
struct PrepArgs {
    const float* t_src[4];   // eWhh0, eWih1, eWhh1, dWhh0 -> [128,512]
    float*       t_dst[4];
    const float* wo1;  float* wo1T;                      // [128,128] transpose
    const float* d1x;  const float* d1h;  float* pack;   // dec L1 4-wide pack
};

__global__ void kPrep(PrepArgs a) {
    const int m = blockIdx.x;
    if (m < 4) {
        for (int i = threadIdx.x; i < G_ * H_; i += blockDim.x) {
            const int j = i >> 7, k = i & 127;
            a.t_dst[m][k * G_ + j] = a.t_src[m][i];
        }
    } else if (m == 4) {
        for (int i = threadIdx.x; i < H_ * H_; i += blockDim.x) {
            const int j = i >> 7, k = i & 127;
            a.wo1T[k * H_ + j] = a.wo1[i];
        }
    } else {
        // pack[(k*256 + j2)*4] = {Wih1[j2][k], Whh1[j2][k], Wih1[j2+256][k], Whh1[j2+256][k]}
        for (int i = threadIdx.x; i < H_ * 256; i += blockDim.x) {
            const int k = i >> 8, j2 = i & 255;
            float* p = a.pack + ((size_t)k * 256 + j2) * 4;
            p[0] = a.d1x[j2 * H_ + k];
            p[1] = a.d1h[j2 * H_ + k];
            p[2] = a.d1x[(j2 + 256) * H_ + k];
            p[3] = a.d1h[(j2 + 256) * H_ + k];
        }
    }
}

// ------------------------------------------- enc L0 (dual-gate split-k) -----
__global__ __launch_bounds__(512, 2) void kA(
    const float* __restrict__ feat,   // [B,T]
    const float* __restrict__ whhT,   // [128,512] enc_Whh0^T
    const float* __restrict__ wih0,   // [512]
    const float* __restrict__ bias,   // [512]
    float* __restrict__ ys0T,         // [CL][128][1024] k-major
    float* __restrict__ hS, float* __restrict__ cS,
    int t0, int CL)
{
    __shared__ __align__(16) float h_sh[H_ * 4];     // [hid][bb]
    __shared__ __align__(16) float zp[2 * 4 * G_];   // [kh][batch][gate]
    __shared__ __align__(16) float f_sh[84 * 4];

    const int tid = threadIdx.x;
    const int j2  = tid & 255;         // gate pair base: gates j2, j2+256
    const int kh  = tid >> 8;          // k-half
    const int B0  = blockIdx.x * 4;

    float w0[64], w1[64];
#pragma unroll
    for (int k = 0; k < 64; k++) {
        w0[k] = whhT[(kh * 64 + k) * G_ + j2];
        w1[k] = whhT[(kh * 64 + k) * G_ + j2 + 256];
    }
    const float wx0 = wih0[j2],  bj0 = bias[j2];
    const float wx1 = wih0[j2 + 256], bj1 = bias[j2 + 256];

    for (int i = tid; i < CL * 4; i += 512)
        f_sh[i] = feat[(B0 + (i & 3)) * T_ + t0 + (i >> 2)];

    const int hid = tid & 127, bb = tid >> 7;
    float c = 0.f;
    {
        float hv = 0.f;
        if (t0 != 0) { c = cS[(B0 + bb) * H_ + hid]; hv = hS[(B0 + bb) * H_ + hid]; }
        h_sh[hid * 4 + bb] = hv;
    }
    __syncthreads();

    const float* hb = h_sh + kh * 256;
    for (int dt = 0; dt < CL; dt++) {
        // pipelined k-major store of previous step's h (valid until act below)
        if (dt > 0)
            ys0T[((size_t)(dt - 1) * H_ + (tid >> 2)) * B_ + B0 + (tid & 3)] = h_sh[tid];

        float a0, a1, a2, a3, e0, e1, e2, e3;
        if (kh == 0) {
            const float4 xv = *(const float4*)&f_sh[dt * 4];
            a0 = __fmaf_rn(xv.x, wx0, bj0); a1 = __fmaf_rn(xv.y, wx0, bj0);
            a2 = __fmaf_rn(xv.z, wx0, bj0); a3 = __fmaf_rn(xv.w, wx0, bj0);
            e0 = __fmaf_rn(xv.x, wx1, bj1); e1 = __fmaf_rn(xv.y, wx1, bj1);
            e2 = __fmaf_rn(xv.z, wx1, bj1); e3 = __fmaf_rn(xv.w, wx1, bj1);
        } else { a0=a1=a2=a3=e0=e1=e2=e3=0.f; }
#pragma unroll
        for (int k = 0; k < 64; k++) {
            const float4 h4 = *(const float4*)&hb[k * 4];   // uniform broadcast
            a0 = __fmaf_rn(h4.x, w0[k], a0); a1 = __fmaf_rn(h4.y, w0[k], a1);
            a2 = __fmaf_rn(h4.z, w0[k], a2); a3 = __fmaf_rn(h4.w, w0[k], a3);
            e0 = __fmaf_rn(h4.x, w1[k], e0); e1 = __fmaf_rn(h4.y, w1[k], e1);
            e2 = __fmaf_rn(h4.z, w1[k], e2); e3 = __fmaf_rn(h4.w, w1[k], e3);
        }
        float* zb = zp + kh * 2048;
        zb[0*G_ + j2] = a0; zb[1*G_ + j2] = a1; zb[2*G_ + j2] = a2; zb[3*G_ + j2] = a3;
        zb[0*G_ + j2+256] = e0; zb[1*G_ + j2+256] = e1; zb[2*G_ + j2+256] = e2; zb[3*G_ + j2+256] = e3;
        __syncthreads();

        {
            const int base = bb * G_ + hid;
            const float zi = zp[base]          + zp[2048 + base];
            const float zf = zp[base + H_]     + zp[2048 + base + H_];
            const float zg = zp[base + 2*H_]   + zp[2048 + base + 2*H_];
            const float zo = zp[base + 3*H_]   + zp[2048 + base + 3*H_];
            c = sigm(zf) * c + sigm(zi) * tanh_f(zg);
            h_sh[hid * 4 + bb] = sigm(zo) * tanh_f(c);
        }
        __syncthreads();
    }
    ys0T[((size_t)(CL - 1) * H_ + (tid >> 2)) * B_ + B0 + (tid & 3)] = h_sh[tid];
    hS[(B0 + bb) * H_ + hid] = h_sh[hid * 4 + bb];
    cS[(B0 + bb) * H_ + hid] = c;
}

// ------------------------------------------------- X1 GEMM (round-3 fp32) ---
__global__ __launch_bounds__(256, 3) void kX(
    const float* __restrict__ ys0T,   // [CL][128][1024]
    const float* __restrict__ wT,     // [128][512]
    const float* __restrict__ bias,   // [512]
    float* __restrict__ X1)           // [CL][1024][512]
{
    __shared__ __align__(16) float As[64][132];
    __shared__ __align__(16) float Bs[64][68];

    const int tid = threadIdx.x;
    const int m0 = blockIdx.x * 128;
    const int n0 = blockIdx.y * 64;
    const int dt = blockIdx.z;
    const float* A = ys0T + (size_t)dt * H_ * B_;

    const int tx = tid & 15, ty = tid >> 4;
    float acc[8][4] = {};

#pragma unroll
    for (int ks = 0; ks < 2; ks++) {
        if (ks) __syncthreads();
        for (int t = tid; t < 64 * 32; t += 256) {
            const int r = t >> 5, q = t & 31;
            *(float4*)&As[r][q * 4] = *(const float4*)&A[(size_t)(ks * 64 + r) * B_ + m0 + q * 4];
        }
        for (int t = tid; t < 64 * 16; t += 256) {
            const int r = t >> 4, q = t & 15;
            *(float4*)&Bs[r][q * 4] = *(const float4*)&wT[(size_t)(ks * 64 + r) * G_ + n0 + q * 4];
        }
        __syncthreads();

#pragma unroll 4
        for (int k = 0; k < 64; k++) {
            float av[8];
            *(float4*)&av[0] = *(const float4*)&As[k][ty * 8];
            *(float4*)&av[4] = *(const float4*)&As[k][ty * 8 + 4];
            const float4 bv = *(const float4*)&Bs[k][tx * 4];
#pragma unroll
            for (int i = 0; i < 8; i++) {
                acc[i][0] = __fmaf_rn(av[i], bv.x, acc[i][0]);
                acc[i][1] = __fmaf_rn(av[i], bv.y, acc[i][1]);
                acc[i][2] = __fmaf_rn(av[i], bv.z, acc[i][2]);
                acc[i][3] = __fmaf_rn(av[i], bv.w, acc[i][3]);
            }
        }
    }

    const float4 bvb = *(const float4*)&bias[n0 + tx * 4];
#pragma unroll
    for (int i = 0; i < 8; i++) {
        float4 o;
        o.x = acc[i][0] + bvb.x; o.y = acc[i][1] + bvb.y;
        o.z = acc[i][2] + bvb.z; o.w = acc[i][3] + bvb.w;
        *(float4*)&X1[((size_t)dt * B_ + m0 + ty * 8 + i) * G_ + n0 + tx * 4] = o;
    }
}

// ------------------------------------------- enc L1 (dual-gate split-k) -----
__global__ __launch_bounds__(512, 2) void kB2(
    const float* __restrict__ X1,     // [CL][B][512] x-projection (+bias)
    const float* __restrict__ whhT,   // [128,512] enc_Whh1^T
    float* __restrict__ hS, float* __restrict__ cS,
    int t0, int CL)
{
    __shared__ __align__(16) float h_sh[H_ * 4];
    __shared__ __align__(16) float zp[2 * 4 * G_];

    const int tid = threadIdx.x;
    const int j2  = tid & 255;
    const int kh  = tid >> 8;
    const int B0  = blockIdx.x * 4;

    float w0[64], w1[64];
#pragma unroll
    for (int k = 0; k < 64; k++) {
        w0[k] = whhT[(kh * 64 + k) * G_ + j2];
        w1[k] = whhT[(kh * 64 + k) * G_ + j2 + 256];
    }

    const int hid = tid & 127, bb = tid >> 7;
    float c = 0.f;
    {
        float hv = 0.f;
        if (t0 != 0) { c = cS[(B0 + bb) * H_ + hid]; hv = hS[(B0 + bb) * H_ + hid]; }
        h_sh[hid * 4 + bb] = hv;
    }
    __syncthreads();

    const float* hb = h_sh + kh * 256;
    for (int dt = 0; dt < CL; dt++) {
        // prefetch this step's x-projection for the act role (hides L2/L3 latency)
        const size_t xb = ((size_t)dt * B_ + B0 + bb) * G_ + hid;
        const float xg0 = X1[xb];
        const float xg1 = X1[xb + H_];
        const float xg2 = X1[xb + 2 * H_];
        const float xg3 = X1[xb + 3 * H_];

        float a0=0.f,a1=0.f,a2=0.f,a3=0.f,e0=0.f,e1=0.f,e2=0.f,e3=0.f;
#pragma unroll
        for (int k = 0; k < 64; k++) {
            const float4 h4 = *(const float4*)&hb[k * 4];
            a0 = __fmaf_rn(h4.x, w0[k], a0); a1 = __fmaf_rn(h4.y, w0[k], a1);
            a2 = __fmaf_rn(h4.z, w0[k], a2); a3 = __fmaf_rn(h4.w, w0[k], a3);
            e0 = __fmaf_rn(h4.x, w1[k], e0); e1 = __fmaf_rn(h4.y, w1[k], e1);
            e2 = __fmaf_rn(h4.z, w1[k], e2); e3 = __fmaf_rn(h4.w, w1[k], e3);
        }
        float* zb = zp + kh * 2048;
        zb[0*G_ + j2] = a0; zb[1*G_ + j2] = a1; zb[2*G_ + j2] = a2; zb[3*G_ + j2] = a3;
        zb[0*G_ + j2+256] = e0; zb[1*G_ + j2+256] = e1; zb[2*G_ + j2+256] = e2; zb[3*G_ + j2+256] = e3;
        __syncthreads();

        {
            const int base = bb * G_ + hid;
            const float zi = zp[base]          + zp[2048 + base]          + xg0;
            const float zf = zp[base + H_]     + zp[2048 + base + H_]     + xg1;
            const float zg = zp[base + 2*H_]   + zp[2048 + base + 2*H_]   + xg2;
            const float zo = zp[base + 3*H_]   + zp[2048 + base + 3*H_]   + xg3;
            c = sigm(zf) * c + sigm(zi) * tanh_f(zg);
            h_sh[hid * 4 + bb] = sigm(zo) * tanh_f(c);
        }
        __syncthreads();
    }
    hS[(B0 + bb) * H_ + hid] = h_sh[hid * 4 + bb];
    cS[(B0 + bb) * H_ + hid] = c;
}

// ------------------------------------------- decoder (dual-gate split-k) ----
__global__ __launch_bounds__(512, 2) void kD(
    const float* __restrict__ h1S, const float* __restrict__ c1S,
    const float* __restrict__ h2S, const float* __restrict__ c2S,
    const float* __restrict__ whh0T,  // [128][512] dec_Whh0^T (register-resident)
    const float* __restrict__ wih0,   // [512]
    const float* __restrict__ b0,
    const float* __restrict__ packD1, // [128][256][4] {xW,hW,xW+256,hW+256}
    const float* __restrict__ b1,
    const float* __restrict__ wo1T,   // [128][128] -> LDS
    const float* __restrict__ bo1,
    const float* __restrict__ wo2,
    const float* __restrict__ bo2,
    float* __restrict__ out)          // [B,TGT]
{
    __shared__ __align__(16) float h1_sh[H_ * 4];
    __shared__ __align__(16) float h2_sh[H_ * 4];
    __shared__ __align__(16) float h2t[4][H_];       // [bb][hid] for head b128
    __shared__ __align__(16) float zp[2 * 4 * G_];
    __shared__ __align__(16) float wo1s[H_ * H_];    // 64 KB
    __shared__ __align__(16) float x_sh[4];
    __shared__ float rp[8];

    const int tid = threadIdx.x;
    const int j2  = tid & 255;
    const int kh  = tid >> 8;
    const int B0  = blockIdx.x * 4;

    float w0[64], w1[64];
#pragma unroll
    for (int k = 0; k < 64; k++) {
        w0[k] = whh0T[(kh * 64 + k) * G_ + j2];
        w1[k] = whh0T[(kh * 64 + k) * G_ + j2 + 256];
    }
    const float wx0 = wih0[j2],  b00 = b0[j2];
    const float wx1 = wih0[j2 + 256], b01 = b0[j2 + 256];
    const float b10 = b1[j2], b11 = b1[j2 + 256];

    for (int t = tid; t < H_ * H_ / 4; t += 512)
        *(float4*)&wo1s[t * 4] = *(const float4*)&wo1T[t * 4];

    const int hid = tid & 127, bb = tid >> 7;
    const float wo2v = wo2[hid];
    const float bo1j = bo1[hid];
    const float bo2v = bo2[0];

    float c1 = c1S[(B0 + bb) * H_ + hid];
    float c2 = c2S[(B0 + bb) * H_ + hid];
    h1_sh[hid * 4 + bb] = h1S[(B0 + bb) * H_ + hid];
    {
        const float h2v = h2S[(B0 + bb) * H_ + hid];
        h2_sh[hid * 4 + bb] = h2v;
        h2t[bb][hid] = h2v;
    }
    if (tid < 4) x_sh[tid] = 0.f;
    __syncthreads();

    const float* hb1 = h1_sh + kh * 256;
    const float* hb2 = h2_sh + kh * 256;
    const float* pk  = packD1 + (size_t)kh * 64 * 1024 + (size_t)j2 * 4;

    for (int s = 0; s < TGT_; s++) {
        // ---- L0 dot (register-resident weights) ----
        float a0, a1, a2, a3, e0, e1, e2, e3;
        if (kh == 0) {
            const float4 xv = *(const float4*)x_sh;
            a0 = __fmaf_rn(xv.x, wx0, b00); a1 = __fmaf_rn(xv.y, wx0, b00);
            a2 = __fmaf_rn(xv.z, wx0, b00); a3 = __fmaf_rn(xv.w, wx0, b00);
            e0 = __fmaf_rn(xv.x, wx1, b01); e1 = __fmaf_rn(xv.y, wx1, b01);
            e2 = __fmaf_rn(xv.z, wx1, b01); e3 = __fmaf_rn(xv.w, wx1, b01);
        } else { a0=a1=a2=a3=e0=e1=e2=e3=0.f; }
#pragma unroll
        for (int k = 0; k < 64; k++) {
            const float4 h4 = *(const float4*)&hb1[k * 4];
            a0 = __fmaf_rn(h4.x, w0[k], a0); a1 = __fmaf_rn(h4.y, w0[k], a1);
            a2 = __fmaf_rn(h4.z, w0[k], a2); a3 = __fmaf_rn(h4.w, w0[k], a3);
            e0 = __fmaf_rn(h4.x, w1[k], e0); e1 = __fmaf_rn(h4.y, w1[k], e1);
            e2 = __fmaf_rn(h4.z, w1[k], e2); e3 = __fmaf_rn(h4.w, w1[k], e3);
        }
        float* zb = zp + kh * 2048;
        zb[0*G_ + j2] = a0; zb[1*G_ + j2] = a1; zb[2*G_ + j2] = a2; zb[3*G_ + j2] = a3;
        zb[0*G_ + j2+256] = e0; zb[1*G_ + j2+256] = e1; zb[2*G_ + j2+256] = e2; zb[3*G_ + j2+256] = e3;
        __syncthreads();

        // ---- L0 act ----
        {
            const int base = bb * G_ + hid;
            const float zi = zp[base]          + zp[2048 + base];
            const float zf = zp[base + H_]     + zp[2048 + base + H_];
            const float zg = zp[base + 2*H_]   + zp[2048 + base + 2*H_];
            const float zo = zp[base + 3*H_]   + zp[2048 + base + 3*H_];
            c1 = sigm(zf) * c1 + sigm(zi) * tanh_f(zg);
            h1_sh[hid * 4 + bb] = sigm(zo) * tanh_f(c1);
        }
        __syncthreads();

        // ---- L1 dot (L2 stream: one float4 per k per thread) ----
        float d0, d1, d2, d3, g0, g1, g2, g3;
        if (kh == 0) { d0=d1=d2=d3=b10; g0=g1=g2=g3=b11; }
        else         { d0=d1=d2=d3=0.f; g0=g1=g2=g3=0.f; }
#pragma unroll 16
        for (int k = 0; k < 64; k++) {
            const float4 wp = *(const float4*)&pk[(size_t)k * 1024];
            const float4 p4 = *(const float4*)&hb1[k * 4];
            const float4 q4 = *(const float4*)&hb2[k * 4];
            d0 = __fmaf_rn(p4.x, wp.x, __fmaf_rn(q4.x, wp.y, d0));
            d1 = __fmaf_rn(p4.y, wp.x, __fmaf_rn(q4.y, wp.y, d1));
            d2 = __fmaf_rn(p4.z, wp.x, __fmaf_rn(q4.z, wp.y, d2));
            d3 = __fmaf_rn(p4.w, wp.x, __fmaf_rn(q4.w, wp.y, d3));
            g0 = __fmaf_rn(p4.x, wp.z, __fmaf_rn(q4.x, wp.w, g0));
            g1 = __fmaf_rn(p4.y, wp.z, __fmaf_rn(q4.y, wp.w, g1));
            g2 = __fmaf_rn(p4.z, wp.z, __fmaf_rn(q4.z, wp.w, g2));
            g3 = __fmaf_rn(p4.w, wp.z, __fmaf_rn(q4.w, wp.w, g3));
        }
        zb[0*G_ + j2] = d0; zb[1*G_ + j2] = d1; zb[2*G_ + j2] = d2; zb[3*G_ + j2] = d3;
        zb[0*G_ + j2+256] = g0; zb[1*G_ + j2+256] = g1; zb[2*G_ + j2+256] = g2; zb[3*G_ + j2+256] = g3;
        __syncthreads();

        // ---- L1 act ----
        {
            const int base = bb * G_ + hid;
            const float zi = zp[base]          + zp[2048 + base];
            const float zf = zp[base + H_]     + zp[2048 + base + H_];
            const float zg = zp[base + 2*H_]   + zp[2048 + base + 2*H_];
            const float zo = zp[base + 3*H_]   + zp[2048 + base + 3*H_];
            c2 = sigm(zf) * c2 + sigm(zi) * tanh_f(zg);
            const float h2v = sigm(zo) * tanh_f(c2);
            h2_sh[hid * 4 + bb] = h2v;
            h2t[bb][hid] = h2v;
        }
        __syncthreads();

        // ---- head: relu(h2 @ Wout1^T + bo1) @ Wout2^T + bo2 ----
        {
            float acc = bo1j;
#pragma unroll 8
            for (int kq = 0; kq < 32; kq++) {
                const float4 hq = *(const float4*)&h2t[bb][kq * 4];  // uniform b128
                acc = __fmaf_rn(hq.x, wo1s[(kq*4+0) * H_ + hid], acc);
                acc = __fmaf_rn(hq.y, wo1s[(kq*4+1) * H_ + hid], acc);
                acc = __fmaf_rn(hq.z, wo1s[(kq*4+2) * H_ + hid], acc);
                acc = __fmaf_rn(hq.w, wo1s[(kq*4+3) * H_ + hid], acc);
            }
            float p = fmaxf(acc, 0.f) * wo2v;
            p += __shfl_down(p, 32);
            p += __shfl_down(p, 16);
            p += __shfl_down(p, 8);
            p += __shfl_down(p, 4);
            p += __shfl_down(p, 2);
            p += __shfl_down(p, 1);
            if ((tid & 63) == 0) rp[tid >> 6] = p;   // wave w: bb = w>>1
        }
        __syncthreads();
        if (tid < 4) {
            const float pr = rp[tid * 2] + rp[tid * 2 + 1] + bo2v;
            out[(B0 + tid) * TGT_ + s] = pr;
            x_sh[tid] = pr;
        }
        __syncthreads();
    }
}

// ---------------------------------------------------------------- launch ----
extern "C" void kernel_launch(void* const* d_in, const int* in_sizes, int n_in,
                              void* d_out, int out_size, void* d_ws, size_t ws_size,
                              hipStream_t stream) {
    const float* feat  = (const float*)d_in[0];
    const float* eWih0 = (const float*)d_in[1];
    const float* eWhh0 = (const float*)d_in[2];
    const float* eB0   = (const float*)d_in[3];
    const float* eWih1 = (const float*)d_in[4];
    const float* eWhh1 = (const float*)d_in[5];
    const float* eB1   = (const float*)d_in[6];
    const float* dWih0 = (const float*)d_in[7];
    const float* dWhh0 = (const float*)d_in[8];
    const float* dB0   = (const float*)d_in[9];
    const float* dWih1 = (const float*)d_in[10];
    const float* dWhh1 = (const float*)d_in[11];
    const float* dB1   = (const float*)d_in[12];
    const float* Wo1   = (const float*)d_in[13];
    const float* bo1   = (const float*)d_in[14];
    const float* Wo2   = (const float*)d_in[15];
    const float* bo2   = (const float*)d_in[16];

    const size_t SZ_BH = (size_t)B_ * H_;     // 131072
    const size_t SZ_W  = (size_t)G_ * H_;     // 65536
    const size_t fixed_f = 4 * SZ_BH + 4 * SZ_W + 2 * SZ_W + (size_t)H_ * H_ + 64;

    static const int cands[] = {84, 56, 48, 42, 28, 24, 21, 16, 14, 12, 8, 7, 6, 4, 3, 2, 1};
    int CL = 1;
    for (int ci = 0; ci < 17; ci++) {
        const size_t need = (fixed_f + (size_t)cands[ci] * B_ * (H_ + G_)) * 4;
        if (need <= ws_size) { CL = cands[ci]; break; }
    }
    const int NC = T_ / CL;

    float* ws    = (float*)d_ws;
    float* ys0T  = ws;                                   // [CL][128][1024]
    float* X1    = ys0T + (size_t)CL * B_ * H_;          // [CL][1024][512]
    float* h1S   = X1 + (size_t)CL * B_ * G_;
    float* c1S   = h1S + SZ_BH;
    float* h2S   = c1S + SZ_BH;
    float* c2S   = h2S + SZ_BH;
    float* wtE0  = c2S + SZ_BH;
    float* wtE1x = wtE0 + SZ_W;
    float* wtE1h = wtE1x + SZ_W;
    float* wtD0  = wtE1h + SZ_W;
    float* wtD1p = wtD0 + SZ_W;            // [128][256][4]
    float* wtO1  = wtD1p + 2 * SZ_W;       // [128][128]

    PrepArgs pa;
    pa.t_src[0] = eWhh0; pa.t_dst[0] = wtE0;
    pa.t_src[1] = eWih1; pa.t_dst[1] = wtE1x;
    pa.t_src[2] = eWhh1; pa.t_dst[2] = wtE1h;
    pa.t_src[3] = dWhh0; pa.t_dst[3] = wtD0;
    pa.wo1 = Wo1; pa.wo1T = wtO1;
    pa.d1x = dWih1; pa.d1h = dWhh1; pa.pack = wtD1p;
    kPrep<<<6, 256, 0, stream>>>(pa);

    for (int c = 0; c < NC; c++) {
        const int t0 = c * CL;
        kA<<<NBLK_, 512, 0, stream>>>(feat, wtE0, eWih0, eB0, ys0T, h1S, c1S, t0, CL);
        kX<<<dim3(8, 8, CL), 256, 0, stream>>>(ys0T, wtE1x, eB1, X1);
        kB2<<<NBLK_, 512, 0, stream>>>(X1, wtE1h, h2S, c2S, t0, CL);
    }
    kD<<<NBLK_, 512, 0, stream>>>(h1S, c1S, h2S, c2S,
                                  wtD0, dWih0, dB0,
                                  wtD1p, dB1,
                                  wtO1, bo1, Wo2, bo2,
                                  (float*)d_out);
}